// Round 16
// baseline (333.192 us; speedup 1.0000x reference)
//
#include <hip/hip_runtime.h>
#include <hip/hip_bf16.h>

typedef unsigned short u16;
typedef unsigned int   u32;

#define TTOK  50176      // 1024 windows * 49
#define CDIM  256

using short8 = __attribute__((ext_vector_type(8))) short;
using f32x4  = __attribute__((ext_vector_type(4))) float;

__device__ __forceinline__ float b2f(u16 u) { return __uint_as_float(((u32)u) << 16); }
// Native cast (RNE) — compiler folds pairs into v_cvt_pk_bf16_f32 (m240).
__device__ __forceinline__ u16 f2b(float f) {
    union { __hip_bfloat16 h; u16 u; } cv;
    cv.h = __float2bfloat16(f);
    return cv.u;
}

#define GLD16(src, dst) __builtin_amdgcn_global_load_lds( \
    (const __attribute__((address_space(1))) void*)(src),  \
    (__attribute__((address_space(3))) void*)(dst), 16, 0, 0)

// ---------------------------------------------------------------------------
// Merged prep: [0,928) pad+transpose x -> xpad ; [928,2080) conv_w -> W2 ;
// [2080,2848) qkv/proj/fc1/fc2 fp32 -> bf16. Disjoint outputs, no ordering.
// ---------------------------------------------------------------------------
__global__ __launch_bounds__(256) void prep_k(const float* __restrict__ x, u16* __restrict__ xp,
                                              const float* __restrict__ cw, u16* __restrict__ W2,
                                              const float* __restrict__ qw, const float* __restrict__ pw,
                                              const float* __restrict__ f1w, const float* __restrict__ f2w,
                                              u16* __restrict__ wdst) {
    __shared__ float tile[128][58];
    int bid = blockIdx.x;
    int tid = threadIdx.x;
    if (bid < 928) {
        int b = bid / 58, hp = bid - b * 58;
        bool zrow = (hp == 0 || hp == 57);
        if (!zrow) {
            int h = hp - 1;
            for (int e = tid; e < 128 * 14; e += 256) {
                int ic = e / 14, j = e - ic * 14;
                float4 v = *(const float4*)&x[(((size_t)b * 128 + ic) * 56 + h) * 56 + j * 4];
                tile[ic][j * 4 + 0] = v.x; tile[ic][j * 4 + 1] = v.y;
                tile[ic][j * 4 + 2] = v.z; tile[ic][j * 4 + 3] = v.w;
            }
            __syncthreads();
        }
        size_t rb = ((size_t)b * 58 + hp) * 58 * 128;
        for (int u = tid; u < 58 * 16; u += 256) {
            int wp = u / 16, icg = u - wp * 16;
            uint4 o = make_uint4(0u, 0u, 0u, 0u);
            if (!zrow && wp != 0 && wp != 57) {
                int w = wp - 1, ic0 = icg * 8;
                u16 v0 = f2b(tile[ic0 + 0][w]), v1 = f2b(tile[ic0 + 1][w]);
                u16 v2 = f2b(tile[ic0 + 2][w]), v3 = f2b(tile[ic0 + 3][w]);
                u16 v4 = f2b(tile[ic0 + 4][w]), v5 = f2b(tile[ic0 + 5][w]);
                u16 v6 = f2b(tile[ic0 + 6][w]), v7 = f2b(tile[ic0 + 7][w]);
                o.x = (u32)v0 | ((u32)v1 << 16);
                o.y = (u32)v2 | ((u32)v3 << 16);
                o.z = (u32)v4 | ((u32)v5 << 16);
                o.w = (u32)v6 | ((u32)v7 << 16);
            }
            *(uint4*)&xp[rb + (size_t)wp * 128 + icg * 8] = o;
        }
    } else if (bid < 2080) {
        int e = (bid - 928) * 256 + tid;     // < 294912
        int o = e / 1152, rem = e - o * 1152;
        int tap = rem >> 7, ic = rem & 127;
        W2[e] = f2b(cw[(o * 128 + ic) * 9 + tap]);
    } else {
        int i = (bid - 2080) * 256 + tid;    // < 196608
        const float* src; int off;
        if (i < 49152)       { src = qw;  off = i; }
        else if (i < 65536)  { src = pw;  off = i - 49152; }
        else if (i < 131072) { src = f1w; off = i - 65536; }
        else                 { src = f2w; off = i - 131072; }
        float4 v = *(const float4*)&src[off * 4];
        ushort4 o;
        o.x = f2b(v.x); o.y = f2b(v.y); o.z = f2b(v.z); o.w = f2b(v.w);
        *(ushort4*)&wdst[i * 4] = o;
    }
}

// ---------------------------------------------------------------------------
// XCD remaps: contiguous stripes per XCD for A-panel L2 reuse.
// ---------------------------------------------------------------------------
__device__ __forceinline__ void xcd_remap(int& bx, int& by) {
    int nx = gridDim.x, ny = gridDim.y;
    if ((ny & 7) == 0) {
        int linear = blockIdx.y * nx + blockIdx.x;
        int xcd = linear & 7, within = linear >> 3;
        bx = within % nx;
        by = xcd * (ny >> 3) + within / nx;
    } else { bx = blockIdx.x; by = blockIdx.y; }
}

__device__ __forceinline__ int xcd_remap1d() {
    int nb = gridDim.x, lin = blockIdx.x;
    int q = nb >> 3, r = nb & 7;
    int xcd = lin & 7, idx = lin >> 3;
    return (xcd < r ? xcd * (q + 1) : r * (q + 1) + (xcd - r) * q) + idx;
}

// ---------------------------------------------------------------------------
// Fused implicit conv GEMM + bias + LayerNorm(g1,b1).
// 64 rows x 256 cols, BK=32 double-buffered 2-phase, grid 784, LDS 40KB.
// ---------------------------------------------------------------------------
__global__ __launch_bounds__(256) void gemm_conv_ln_k(const u16* __restrict__ xp, const u16* __restrict__ W2,
                                                      const float* __restrict__ bias,
                                                      const float* __restrict__ gam, const float* __restrict__ bet,
                                                      u16* __restrict__ C) {
    __shared__ __align__(16) u16 lsA[2][64 * 32];
    __shared__ __align__(16) u16 lsB[2][256 * 32];
    int tid = threadIdx.x;
    int wave = tid >> 6, lane = tid & 63;
    int by = xcd_remap1d();
    int mBase = by * 64;
    int wm = wave >> 1, wn = wave & 1;
    int lr = lane & 15, lq = lane >> 4;
    int rr4 = lane >> 2, kc = lane & 3;
    int kcs = (kc ^ ((rr4 >> 1) & 3)) * 8;     // pre-swizzled k-chunk (elems)

    size_t tbA;
    {
        int t = mBase + wave * 16 + rr4;
        int win = t / 49, n = t - win * 49;
        int b = win >> 6, wh = (win >> 3) & 7, ww = win & 7;
        int r = n / 7, s = n - r * 7;
        tbA = ((size_t)(b * 58 + wh * 7 + r) * 58 + ww * 7 + s) * 128 + kcs;
    }
    const u16* gB[4];
#pragma unroll
    for (int j = 0; j < 4; ++j)
        gB[j] = W2 + (size_t)(j * 64 + wave * 16 + rr4) * 1152 + kcs;

    f32x4 acc[2][8];
#pragma unroll
    for (int m = 0; m < 2; ++m)
#pragma unroll
        for (int n = 0; n < 8; ++n) acc[m][n] = (f32x4){0.f, 0.f, 0.f, 0.f};

#define CONV_STAGE(ks, buf) do { \
        int tap_ = (ks) >> 2, qz_ = (ks) & 3; \
        int kh_ = tap_ / 3, kw_ = tap_ - kh_ * 3; \
        GLD16(xp + tbA + (kh_ * 58 + kw_) * 128 + qz_ * 32, &lsA[buf][(wave * 16) * 32]); \
        _Pragma("unroll") \
        for (int j_ = 0; j_ < 4; ++j_) \
            GLD16(gB[j_] + (ks) * 32, &lsB[buf][(j_ * 64 + wave * 16) * 32]); \
    } while (0)

    CONV_STAGE(0, 0);
    __syncthreads();
    int slq = (lq ^ ((lr >> 1) & 3)) * 8;
    for (int ks = 0; ks < 36; ++ks) {
        int cur = ks & 1;
        if (ks + 1 < 36) CONV_STAGE(ks + 1, cur ^ 1);
        short8 af[2], bf[8];
#pragma unroll
        for (int m = 0; m < 2; ++m)
            af[m] = *(const short8*)&lsA[cur][(wm * 32 + m * 16 + lr) * 32 + slq];
#pragma unroll
        for (int n = 0; n < 8; ++n)
            bf[n] = *(const short8*)&lsB[cur][(wn * 128 + n * 16 + lr) * 32 + slq];
#pragma unroll
        for (int m = 0; m < 2; ++m)
#pragma unroll
            for (int n = 0; n < 8; ++n)
                acc[m][n] = __builtin_amdgcn_mfma_f32_16x16x32_bf16(af[m], bf[n], acc[m][n], 0, 0, 0);
        __syncthreads();
    }
#undef CONV_STAGE

    float bv[8], gv[8], btv[8];
#pragma unroll
    for (int n = 0; n < 8; ++n) {
        int col = wn * 128 + n * 16 + lr;
        bv[n] = bias[col]; gv[n] = gam[col]; btv[n] = bet[col];
    }
#pragma unroll
    for (int m = 0; m < 2; ++m)
#pragma unroll
        for (int n = 0; n < 8; ++n)
#pragma unroll
            for (int r = 0; r < 4; ++r) acc[m][n][r] += bv[n];

    float* red = (float*)lsA;   // 1KB, safe after final barrier
#pragma unroll
    for (int m = 0; m < 2; ++m)
#pragma unroll
        for (int r = 0; r < 4; ++r) {
            float s = 0.f, qq = 0.f;
#pragma unroll
            for (int n = 0; n < 8; ++n) { float v = acc[m][n][r]; s += v; qq += v * v; }
            s += __shfl_xor(s, 1); s += __shfl_xor(s, 2); s += __shfl_xor(s, 4); s += __shfl_xor(s, 8);
            qq += __shfl_xor(qq, 1); qq += __shfl_xor(qq, 2); qq += __shfl_xor(qq, 4); qq += __shfl_xor(qq, 8);
            if (lr == 0) {
                int row = wm * 32 + m * 16 + lq * 4 + r;
                red[row * 4 + wn * 2] = s; red[row * 4 + wn * 2 + 1] = qq;
            }
        }
    __syncthreads();

#pragma unroll
    for (int m = 0; m < 2; ++m)
#pragma unroll
        for (int r = 0; r < 4; ++r) {
            int row = wm * 32 + m * 16 + lq * 4 + r;
            float S = red[row * 4] + red[row * 4 + 2];
            float Q = red[row * 4 + 1] + red[row * 4 + 3];
            float mean = S * (1.f / 256.f);
            float var = Q * (1.f / 256.f) - mean * mean;
            float inv = rsqrtf(var + 1e-5f);
            size_t grow = (size_t)(mBase + row) * 256;
#pragma unroll
            for (int n = 0; n < 8; ++n) {
                int col = wn * 128 + n * 16 + lr;
                C[grow + col] = f2b((acc[m][n][r] - mean) * inv * gv[n] + btv[n]);
            }
        }
}

// ---------------------------------------------------------------------------
// Fused GEMM (N=256) + bias + LayerNorm: 64x256 tile, BK=32 dbuf, grid 784.
// ---------------------------------------------------------------------------
__global__ __launch_bounds__(256) void gemm_ln_k(const u16* __restrict__ A, const u16* __restrict__ Bw,
                                                 const float* __restrict__ bias,
                                                 const float* __restrict__ gam, const float* __restrict__ bet,
                                                 u16* __restrict__ C, int K) {
    __shared__ __align__(16) u16 lsA[2][64 * 32];
    __shared__ __align__(16) u16 lsB[2][256 * 32];
    int tid = threadIdx.x;
    int wave = tid >> 6, lane = tid & 63;
    int by = xcd_remap1d();
    int mBase = by * 64;
    int wm = wave >> 1, wn = wave & 1;
    int lr = lane & 15, lq = lane >> 4;
    int rr4 = lane >> 2, kc = lane & 3;
    int kcs = (kc ^ ((rr4 >> 1) & 3)) * 8;

    const u16* gA = A + (size_t)(mBase + wave * 16 + rr4) * K + kcs;
    const u16* gB[4];
#pragma unroll
    for (int j = 0; j < 4; ++j)
        gB[j] = Bw + (size_t)(j * 64 + wave * 16 + rr4) * K + kcs;

    f32x4 acc[2][8];
#pragma unroll
    for (int m = 0; m < 2; ++m)
#pragma unroll
        for (int n = 0; n < 8; ++n) acc[m][n] = (f32x4){0.f, 0.f, 0.f, 0.f};

#define LN_STAGE(ks, buf) do { \
        GLD16(gA + (ks) * 32, &lsA[buf][(wave * 16) * 32]); \
        _Pragma("unroll") \
        for (int j_ = 0; j_ < 4; ++j_) \
            GLD16(gB[j_] + (ks) * 32, &lsB[buf][(j_ * 64 + wave * 16) * 32]); \
    } while (0)

    int nk = K >> 5;
    LN_STAGE(0, 0);
    __syncthreads();
    int slq = (lq ^ ((lr >> 1) & 3)) * 8;
    for (int ks = 0; ks < nk; ++ks) {
        int cur = ks & 1;
        if (ks + 1 < nk) LN_STAGE(ks + 1, cur ^ 1);
        short8 af[2], bf[8];
#pragma unroll
        for (int m = 0; m < 2; ++m)
            af[m] = *(const short8*)&lsA[cur][(wm * 32 + m * 16 + lr) * 32 + slq];
#pragma unroll
        for (int n = 0; n < 8; ++n)
            bf[n] = *(const short8*)&lsB[cur][(wn * 128 + n * 16 + lr) * 32 + slq];
#pragma unroll
        for (int m = 0; m < 2; ++m)
#pragma unroll
            for (int n = 0; n < 8; ++n)
                acc[m][n] = __builtin_amdgcn_mfma_f32_16x16x32_bf16(af[m], bf[n], acc[m][n], 0, 0, 0);
        __syncthreads();
    }
#undef LN_STAGE

    float bv[8], gv[8], btv[8];
#pragma unroll
    for (int n = 0; n < 8; ++n) {
        int col = wn * 128 + n * 16 + lr;
        bv[n] = bias[col]; gv[n] = gam[col]; btv[n] = bet[col];
    }
#pragma unroll
    for (int m = 0; m < 2; ++m)
#pragma unroll
        for (int n = 0; n < 8; ++n)
#pragma unroll
            for (int r = 0; r < 4; ++r) acc[m][n][r] += bv[n];

    float* red = (float*)lsA;
#pragma unroll
    for (int m = 0; m < 2; ++m)
#pragma unroll
        for (int r = 0; r < 4; ++r) {
            float s = 0.f, qq = 0.f;
#pragma unroll
            for (int n = 0; n < 8; ++n) { float v = acc[m][n][r]; s += v; qq += v * v; }
            s += __shfl_xor(s, 1); s += __shfl_xor(s, 2); s += __shfl_xor(s, 4); s += __shfl_xor(s, 8);
            qq += __shfl_xor(qq, 1); qq += __shfl_xor(qq, 2); qq += __shfl_xor(qq, 4); qq += __shfl_xor(qq, 8);
            if (lr == 0) {
                int row = wm * 32 + m * 16 + lq * 4 + r;
                red[row * 4 + wn * 2] = s; red[row * 4 + wn * 2 + 1] = qq;
            }
        }
    __syncthreads();

#pragma unroll
    for (int m = 0; m < 2; ++m)
#pragma unroll
        for (int r = 0; r < 4; ++r) {
            int row = wm * 32 + m * 16 + lq * 4 + r;
            float S = red[row * 4] + red[row * 4 + 2];
            float Q = red[row * 4 + 1] + red[row * 4 + 3];
            float mean = S * (1.f / 256.f);
            float var = Q * (1.f / 256.f) - mean * mean;
            float inv = rsqrtf(var + 1e-5f);
            size_t grow = (size_t)(mBase + row) * 256;
#pragma unroll
            for (int n = 0; n < 8; ++n) {
                int col = wn * 128 + n * 16 + lr;
                C[grow + col] = f2b((acc[m][n][r] - mean) * inv * gv[n] + btv[n]);
            }
        }
}

// ---------------------------------------------------------------------------
// GEMM, 2-phase double-buffered: 128x128 tile, BK=32, one barrier per K-step;
// next tile's global_load_lds issued BEFORE compute. Coalesced scalar stores.
// EPI: 0 none, 1 +bias, 2 +bias+gelu(tanh)
// ---------------------------------------------------------------------------
template <int EPI>
__global__ __launch_bounds__(256) void gemm_k(const u16* __restrict__ A, const u16* __restrict__ Bw,
                                              const float* __restrict__ bias, u16* __restrict__ C,
                                              int M, int N, int K) {
    __shared__ __align__(16) u16 lsA[2][128 * 32];
    __shared__ __align__(16) u16 lsB[2][128 * 32];
    int tid = threadIdx.x;
    int wave = tid >> 6, lane = tid & 63;
    int bx, by; xcd_remap(bx, by);
    int mBase = by * 128, nBase = bx * 128;
    int wm = wave >> 1, wn = wave & 1;
    int lr = lane & 15, lq = lane >> 4;
    int rr = lane >> 2, kc = lane & 3;
    int kcs = (kc ^ ((rr >> 1) & 3)) * 8;   // pre-swizzled global chunk (elems)

    const u16* gA[2]; const u16* gB[2];
#pragma unroll
    for (int j = 0; j < 2; ++j) {
        int row = wave * 32 + j * 16 + rr;
        gA[j] = A  + (size_t)(mBase + row) * K + kcs;
        gB[j] = Bw + (size_t)(nBase + row) * K + kcs;
    }

    f32x4 acc[4][4];
#pragma unroll
    for (int m = 0; m < 4; ++m)
#pragma unroll
        for (int n = 0; n < 4; ++n) acc[m][n] = (f32x4){0.f, 0.f, 0.f, 0.f};

    int nk = K >> 5;
#pragma unroll
    for (int j = 0; j < 2; ++j) {
        GLD16(gA[j], &lsA[0][(wave * 32 + j * 16) * 32]);
        GLD16(gB[j], &lsB[0][(wave * 32 + j * 16) * 32]);
    }
    __syncthreads();

    int slq = (lq ^ ((lr >> 1) & 3)) * 8;
    for (int ks = 0; ks < nk; ++ks) {
        int cur = ks & 1;
        if (ks + 1 < nk) {
            int nxt = cur ^ 1;
            int ko = (ks + 1) << 5;
#pragma unroll
            for (int j = 0; j < 2; ++j) {
                GLD16(gA[j] + ko, &lsA[nxt][(wave * 32 + j * 16) * 32]);
                GLD16(gB[j] + ko, &lsB[nxt][(wave * 32 + j * 16) * 32]);
            }
        }
        short8 af[4], bf[4];
#pragma unroll
        for (int m = 0; m < 4; ++m)
            af[m] = *(const short8*)&lsA[cur][(wm * 64 + m * 16 + lr) * 32 + slq];
#pragma unroll
        for (int n = 0; n < 4; ++n)
            bf[n] = *(const short8*)&lsB[cur][(wn * 64 + n * 16 + lr) * 32 + slq];
#pragma unroll
        for (int m = 0; m < 4; ++m)
#pragma unroll
            for (int n = 0; n < 4; ++n)
                acc[m][n] = __builtin_amdgcn_mfma_f32_16x16x32_bf16(af[m], bf[n], acc[m][n], 0, 0, 0);
        __syncthreads();   // drains next-tile loads + guards buffer reuse
    }

#pragma unroll
    for (int m = 0; m < 4; ++m) {
        int row0 = mBase + wm * 64 + m * 16 + lq * 4;
#pragma unroll
        for (int n = 0; n < 4; ++n) {
            int col = nBase + wn * 64 + n * 16 + lr;
            float bv = (EPI >= 1) ? bias[col] : 0.f;
#pragma unroll
            for (int r = 0; r < 4; ++r) {
                float v = acc[m][n][r] + bv;
                if (EPI == 2) {
                    float u = 0.79788456f * (v + 0.044715f * v * v * v);
                    float e = __expf(-2.f * u);
                    v = v * __frcp_rn(1.f + e);
                }
                C[(size_t)(row0 + r) * N + col] = f2b(v);
            }
        }
    }
}

// ---------------------------------------------------------------------------
// MFMA window attention: one wave per (window, head), 4 waves/block.
// ---------------------------------------------------------------------------
__global__ __launch_bounds__(256) void attn_mfma_k(const u16* __restrict__ qkv,
                                                   const float* __restrict__ tab,
                                                   u16* __restrict__ out) {
    __shared__ __align__(16) u16 sh[28488];
    int tid = threadIdx.x;
    int wave = tid >> 6, lane = tid & 63;
    int wh = blockIdx.x * 4 + wave;
    int win = wh >> 3, head = wh & 7;
    int g = lane >> 4, cc = lane & 15;

    u16* Pl = sh + wave * 4608;
    u16* Vl = sh + 18432 + wave * 2176;
    float* bs = (float*)(sh + 27136) + wave * 169;

    const size_t wbase = (size_t)win * 49 * 768;
    for (int e = lane; e < 169; e += 64) bs[e] = tab[e * 8 + head];
    for (int e = lane; e < 49 * 16; e += 64) {
        int k = e >> 4, d0 = (e & 15) * 2;
        *(u32*)&Vl[k * 34 + d0] = *(const u32*)&qkv[wbase + (size_t)k * 768 + 512 + head * 32 + d0];
    }
    for (int e = lane; e < 15 * 16; e += 64) {
        int k = 49 + (e >> 4), d0 = (e & 15) * 2;
        *(u32*)&Vl[k * 34 + d0] = 0u;
    }
    __syncthreads();

    short8 aQ[4], bK[4];
#pragma unroll
    for (int t = 0; t < 4; ++t) {
        int qr = t * 16 + cc; if (qr > 48) qr = 48;
        aQ[t] = *(const short8*)&qkv[wbase + (size_t)qr * 768 + head * 32 + g * 8];
        int kr = t * 16 + cc; if (kr > 48) kr = 48;
        bK[t] = *(const short8*)&qkv[wbase + (size_t)kr * 768 + 256 + head * 32 + g * 8];
    }
    f32x4 S[4][4];
#pragma unroll
    for (int a = 0; a < 4; ++a)
#pragma unroll
        for (int b = 0; b < 4; ++b)
            S[a][b] = __builtin_amdgcn_mfma_f32_16x16x32_bf16(aQ[a], bK[b], (f32x4){0.f,0.f,0.f,0.f}, 0, 0, 0);

    int AqA[4][4];
#pragma unroll
    for (int tr = 0; tr < 4; ++tr)
#pragma unroll
        for (int r = 0; r < 4; ++r) {
            int q = tr * 16 + g * 4 + r; if (q > 48) q = 48;
            int dq = (q * 37) >> 8;
            AqA[tr][r] = 6 * dq + q + 84;
        }
    int AcA[4];
    bool colBad[4];
#pragma unroll
    for (int tc = 0; tc < 4; ++tc) {
        int c = tc * 16 + cc;
        colBad[tc] = (c > 48);
        if (c > 48) c = 48;
        int dc = (c * 37) >> 8;
        AcA[tc] = 6 * dc + c;
    }
    const float scale = 0.17677669529663687f;
    float inv[4][4];
#pragma unroll
    for (int tr = 0; tr < 4; ++tr) {
#pragma unroll
        for (int r = 0; r < 4; ++r) {
            float z0 = colBad[0] ? -1e30f : S[tr][0][r] * scale + bs[AqA[tr][r] - AcA[0]];
            float z1 = colBad[1] ? -1e30f : S[tr][1][r] * scale + bs[AqA[tr][r] - AcA[1]];
            float z2 = colBad[2] ? -1e30f : S[tr][2][r] * scale + bs[AqA[tr][r] - AcA[2]];
            float z3 = colBad[3] ? -1e30f : S[tr][3][r] * scale + bs[AqA[tr][r] - AcA[3]];
            float mx = fmaxf(fmaxf(z0, z1), fmaxf(z2, z3));
            mx = fmaxf(mx, __shfl_xor(mx, 1));
            mx = fmaxf(mx, __shfl_xor(mx, 2));
            mx = fmaxf(mx, __shfl_xor(mx, 4));
            mx = fmaxf(mx, __shfl_xor(mx, 8));
            float p0 = __expf(z0 - mx), p1 = __expf(z1 - mx);
            float p2 = __expf(z2 - mx), p3 = __expf(z3 - mx);
            S[tr][0][r] = p0; S[tr][1][r] = p1; S[tr][2][r] = p2; S[tr][3][r] = p3;
            float sm = p0 + p1 + p2 + p3;
            sm += __shfl_xor(sm, 1); sm += __shfl_xor(sm, 2);
            sm += __shfl_xor(sm, 4); sm += __shfl_xor(sm, 8);
            inv[tr][r] = 1.0f / sm;
        }
    }

#pragma unroll
    for (int tr = 0; tr < 4; ++tr)
#pragma unroll
        for (int tc = 0; tc < 4; ++tc) {
            int k = tc * 16 + cc;
            u16* pb = &Pl[tr * 1152 + k * 18 + g * 4];
            u32 w0 = (u32)f2b(S[tr][tc][0]) | ((u32)f2b(S[tr][tc][1]) << 16);
            u32 w1 = (u32)f2b(S[tr][tc][2]) | ((u32)f2b(S[tr][tc][3]) << 16);
            *(u32*)pb = w0;
            *(u32*)(pb + 2) = w1;
        }
    __syncthreads();

    f32x4 O[4][2];
#pragma unroll
    for (int a = 0; a < 4; ++a) { O[a][0] = (f32x4){0.f,0.f,0.f,0.f}; O[a][1] = (f32x4){0.f,0.f,0.f,0.f}; }
#pragma unroll
    for (int s = 0; s < 2; ++s) {
        short8 pa[4], vb[2];
#pragma unroll
        for (int tr = 0; tr < 4; ++tr)
#pragma unroll
            for (int j = 0; j < 8; ++j)
                pa[tr][j] = (short)Pl[tr * 1152 + (s * 32 + g * 8 + j) * 18 + cc];
#pragma unroll
        for (int td = 0; td < 2; ++td)
#pragma unroll
            for (int j = 0; j < 8; ++j)
                vb[td][j] = (short)Vl[(s * 32 + g * 8 + j) * 34 + td * 16 + cc];
#pragma unroll
        for (int tr = 0; tr < 4; ++tr)
#pragma unroll
            for (int td = 0; td < 2; ++td)
                O[tr][td] = __builtin_amdgcn_mfma_f32_16x16x32_bf16(pa[tr], vb[td], O[tr][td], 0, 0, 0);
    }

#pragma unroll
    for (int tr = 0; tr < 4; ++tr)
#pragma unroll
        for (int r = 0; r < 4; ++r) {
            int q = tr * 16 + g * 4 + r;
            if (q < 49) {
                float iv = inv[tr][r];
                u16* op = out + (size_t)(win * 49 + q) * 256 + head * 32;
                op[cc]      = f2b(O[tr][0][r] * iv);
                op[16 + cc] = f2b(O[tr][1][r] * iv);
            }
        }
}

// ---------------------------------------------------------------------------
// LN3 over 2*x then NCHW fp32 output.
// ---------------------------------------------------------------------------
__global__ __launch_bounds__(256) void ln3_out_k(const u16* __restrict__ f, const float* __restrict__ g3,
                                                 const float* __restrict__ b3, float* __restrict__ out) {
    __shared__ float tile[256][57];
    int bh = blockIdx.x;
    int b = bh / 56, h = bh - b * 56;
    int wv = threadIdx.x >> 6, lane = threadIdx.x & 63;
    int wh = h / 7, r = h - wh * 7;
    float4 gg = *(const float4*)&g3[lane * 4];
    float4 bb = *(const float4*)&b3[lane * 4];
    for (int i = 0; i < 14; ++i) {
        int w = wv + i * 4;
        int wwn = w / 7, s2 = w - wwn * 7;
        int t = (b * 64 + wh * 8 + wwn) * 49 + r * 7 + s2;
        ushort4 u = *(const ushort4*)&f[(size_t)t * 256 + lane * 4];
        float v0 = 2.f * b2f(u.x), v1 = 2.f * b2f(u.y), v2 = 2.f * b2f(u.z), v3 = 2.f * b2f(u.w);
        float s = v0 + v1 + v2 + v3;
        float q = v0 * v0 + v1 * v1 + v2 * v2 + v3 * v3;
#pragma unroll
        for (int o = 32; o; o >>= 1) { s += __shfl_xor(s, o); q += __shfl_xor(q, o); }
        float mean = s * (1.f / 256.f);
        float var = q * (1.f / 256.f) - mean * mean;
        float inv = rsqrtf(var + 1e-5f);
        int c = lane * 4;
        tile[c + 0][w] = (v0 - mean) * inv * gg.x + bb.x;
        tile[c + 1][w] = (v1 - mean) * inv * gg.y + bb.y;
        tile[c + 2][w] = (v2 - mean) * inv * gg.z + bb.z;
        tile[c + 3][w] = (v3 - mean) * inv * gg.w + bb.w;
    }
    __syncthreads();
    size_t obase = (size_t)b * 256 * 3136 + (size_t)h * 56;
#pragma unroll
    for (int it = 0; it < 28; ++it) {
        int e = it * 256 + threadIdx.x;   // 0..7167
        int c = e / 28, wu = e - c * 28;
        float2 pack = make_float2(tile[c][wu * 2], tile[c][wu * 2 + 1]);
        *(float2*)&out[obase + (size_t)c * 3136 + wu * 2] = pack;
    }
}

// ---------------------------------------------------------------------------
extern "C" void kernel_launch(void* const* d_in, const int* in_sizes, int n_in,
                              void* d_out, int out_size, void* d_ws, size_t ws_size,
                              hipStream_t stream) {
    (void)in_sizes; (void)n_in; (void)out_size;
    const float* x      = (const float*)d_in[0];
    const float* conv_w = (const float*)d_in[1];
    const float* conv_b = (const float*)d_in[2];
    const float* g1     = (const float*)d_in[3];
    const float* b1     = (const float*)d_in[4];
    const float* g2     = (const float*)d_in[5];
    const float* b2     = (const float*)d_in[6];
    const float* g3     = (const float*)d_in[7];
    const float* b3     = (const float*)d_in[8];
    const float* qkv_w  = (const float*)d_in[9];
    const float* tab    = (const float*)d_in[10];
    const float* proj_w = (const float*)d_in[11];
    const float* proj_b = (const float*)d_in[12];
    const float* fc1_w  = (const float*)d_in[13];
    const float* fc1_b  = (const float*)d_in[14];
    const float* fc2_w  = (const float*)d_in[15];
    const float* fc2_b  = (const float*)d_in[16];
    float* outp = (float*)d_out;

    // ws layout (bytes) — verified fits: 166,985,728
    const size_t OFF_Y  = (size_t)TTOK * 1152 * 2;           // 115,605,504
    const size_t OFF_AT = OFF_Y + (size_t)TTOK * 512;        // +25,690,112
    const size_t NEED   = OFF_AT + (size_t)TTOK * 512;       // 166,985,728
    if (ws_size < NEED) return;

    char* ws = (char*)d_ws;
    u16* xpad    = (u16*)ws;                 // [16][58][58][128]
    u16* ybuf    = (u16*)(ws + OFF_Y);       // [T][256]
    u16* atout   = (u16*)(ws + OFF_AT);      // [T][256]
    u16* qkvbuf  = (u16*)ws;                 // [T][768]  (overwrites dead xpad)
    u16* hidden  = (u16*)ws;                 // [T][1024] (overwrites dead qkvbuf)
    u16* W2      = atout;                    // dead slot until attn
    u16* wbase   = (u16*)(ws + (size_t)TTOK * 1024 * 2);
    u16* qkvw_b  = wbase;                    // 196,608
    u16* projw_b = wbase + 196608;           //  65,536
    u16* fc1w_b  = projw_b + 65536;          // 262,144
    u16* fc2w_b  = fc1w_b + 262144;          // 262,144

    prep_k<<<2848, 256, 0, stream>>>(x, xpad, conv_w, W2, qkv_w, proj_w, fc1_w, fc2_w, qkvw_b);
    gemm_conv_ln_k<<<784, 256, 0, stream>>>(xpad, W2, conv_b, g1, b1, ybuf);
    gemm_k<0><<<dim3(6, 392), 256, 0, stream>>>(ybuf, qkvw_b, nullptr, qkvbuf, TTOK, 768, 256);
    attn_mfma_k<<<2048, 256, 0, stream>>>(qkvbuf, tab, atout);
    gemm_ln_k<<<784, 256, 0, stream>>>(atout, projw_b, proj_b, g2, b2, ybuf, 256);
    gemm_k<2><<<dim3(8, 392), 256, 0, stream>>>(ybuf, fc1w_b, fc1_b, hidden, TTOK, 1024, 256);
    gemm_k<1><<<dim3(2, 392), 256, 0, stream>>>(hidden, fc2w_b, fc2_b, atout, TTOK, 256, 1024);
    ln3_out_k<<<896, 256, 0, stream>>>(atout, g3, b3, outp);
}

// Round 17
// 320.390 us; speedup vs baseline: 1.0400x; 1.0400x over previous
//
#include <hip/hip_runtime.h>
#include <hip/hip_bf16.h>

typedef unsigned short u16;
typedef unsigned int   u32;

#define TTOK  50176      // 1024 windows * 49
#define CDIM  256

using short8 = __attribute__((ext_vector_type(8))) short;
using f32x4  = __attribute__((ext_vector_type(4))) float;

__device__ __forceinline__ float b2f(u16 u) { return __uint_as_float(((u32)u) << 16); }
// Native cast (RNE) — compiler folds pairs into v_cvt_pk_bf16_f32 (m240).
__device__ __forceinline__ u16 f2b(float f) {
    union { __hip_bfloat16 h; u16 u; } cv;
    cv.h = __float2bfloat16(f);
    return cv.u;
}

#define GLD16(src, dst) __builtin_amdgcn_global_load_lds( \
    (const __attribute__((address_space(1))) void*)(src),  \
    (__attribute__((address_space(3))) void*)(dst), 16, 0, 0)

// ---------------------------------------------------------------------------
// Merged prep: [0,928) pad+transpose x -> xpad ; [928,2080) conv_w -> W2 ;
// [2080,2848) qkv/proj/fc1/fc2 fp32 -> bf16. Disjoint outputs, no ordering.
// ---------------------------------------------------------------------------
__global__ __launch_bounds__(256) void prep_k(const float* __restrict__ x, u16* __restrict__ xp,
                                              const float* __restrict__ cw, u16* __restrict__ W2,
                                              const float* __restrict__ qw, const float* __restrict__ pw,
                                              const float* __restrict__ f1w, const float* __restrict__ f2w,
                                              u16* __restrict__ wdst) {
    __shared__ float tile[128][58];
    int bid = blockIdx.x;
    int tid = threadIdx.x;
    if (bid < 928) {
        int b = bid / 58, hp = bid - b * 58;
        bool zrow = (hp == 0 || hp == 57);
        if (!zrow) {
            int h = hp - 1;
            for (int e = tid; e < 128 * 14; e += 256) {
                int ic = e / 14, j = e - ic * 14;
                float4 v = *(const float4*)&x[(((size_t)b * 128 + ic) * 56 + h) * 56 + j * 4];
                tile[ic][j * 4 + 0] = v.x; tile[ic][j * 4 + 1] = v.y;
                tile[ic][j * 4 + 2] = v.z; tile[ic][j * 4 + 3] = v.w;
            }
            __syncthreads();
        }
        size_t rb = ((size_t)b * 58 + hp) * 58 * 128;
        for (int u = tid; u < 58 * 16; u += 256) {
            int wp = u / 16, icg = u - wp * 16;
            uint4 o = make_uint4(0u, 0u, 0u, 0u);
            if (!zrow && wp != 0 && wp != 57) {
                int w = wp - 1, ic0 = icg * 8;
                u16 v0 = f2b(tile[ic0 + 0][w]), v1 = f2b(tile[ic0 + 1][w]);
                u16 v2 = f2b(tile[ic0 + 2][w]), v3 = f2b(tile[ic0 + 3][w]);
                u16 v4 = f2b(tile[ic0 + 4][w]), v5 = f2b(tile[ic0 + 5][w]);
                u16 v6 = f2b(tile[ic0 + 6][w]), v7 = f2b(tile[ic0 + 7][w]);
                o.x = (u32)v0 | ((u32)v1 << 16);
                o.y = (u32)v2 | ((u32)v3 << 16);
                o.z = (u32)v4 | ((u32)v5 << 16);
                o.w = (u32)v6 | ((u32)v7 << 16);
            }
            *(uint4*)&xp[rb + (size_t)wp * 128 + icg * 8] = o;
        }
    } else if (bid < 2080) {
        int e = (bid - 928) * 256 + tid;     // < 294912
        int o = e / 1152, rem = e - o * 1152;
        int tap = rem >> 7, ic = rem & 127;
        W2[e] = f2b(cw[(o * 128 + ic) * 9 + tap]);
    } else {
        int i = (bid - 2080) * 256 + tid;    // < 196608
        const float* src; int off;
        if (i < 49152)       { src = qw;  off = i; }
        else if (i < 65536)  { src = pw;  off = i - 49152; }
        else if (i < 131072) { src = f1w; off = i - 65536; }
        else                 { src = f2w; off = i - 131072; }
        float4 v = *(const float4*)&src[off * 4];
        ushort4 o;
        o.x = f2b(v.x); o.y = f2b(v.y); o.z = f2b(v.z); o.w = f2b(v.w);
        *(ushort4*)&wdst[i * 4] = o;
    }
}

// ---------------------------------------------------------------------------
// XCD remaps: contiguous stripes per XCD for A-panel L2 reuse.
// ---------------------------------------------------------------------------
__device__ __forceinline__ void xcd_remap(int& bx, int& by) {
    int nx = gridDim.x, ny = gridDim.y;
    if ((ny & 7) == 0) {
        int linear = blockIdx.y * nx + blockIdx.x;
        int xcd = linear & 7, within = linear >> 3;
        bx = within % nx;
        by = xcd * (ny >> 3) + within / nx;
    } else { bx = blockIdx.x; by = blockIdx.y; }
}

__device__ __forceinline__ int xcd_remap1d() {
    int nb = gridDim.x, lin = blockIdx.x;
    int q = nb >> 3, r = nb & 7;
    int xcd = lin & 7, idx = lin >> 3;
    return (xcd < r ? xcd * (q + 1) : r * (q + 1) + (xcd - r) * q) + idx;
}

// ---------------------------------------------------------------------------
// Fused implicit conv GEMM + bias + LayerNorm(g1,b1).
// 64 rows x 256 cols, BK=64, 4 waves of 32x128, grid 784, LDS 40KB.
// ---------------------------------------------------------------------------
__global__ __launch_bounds__(256) void gemm_conv_ln_k(const u16* __restrict__ xp, const u16* __restrict__ W2,
                                                      const float* __restrict__ bias,
                                                      const float* __restrict__ gam, const float* __restrict__ bet,
                                                      u16* __restrict__ C) {
    __shared__ __align__(16) u16 lsA[64 * 64];
    __shared__ __align__(16) u16 lsB[256 * 64];
    int tid = threadIdx.x;
    int wave = tid >> 6, lane = tid & 63;
    int by = xcd_remap1d();
    int mBase = by * 64;
    int wm = wave >> 1, wn = wave & 1;
    int lr = lane & 15, lq = lane >> 4;
    int r8 = lane >> 3, kg = lane & 7;
    int kgsw = ((kg ^ r8) & 7) * 8;

    size_t tb[2]; const u16* gB[8];
#pragma unroll
    for (int j = 0; j < 2; ++j) {
        int t = mBase + wave * 16 + j * 8 + r8;
        int win = t / 49, n = t - win * 49;
        int b = win >> 6, wh = (win >> 3) & 7, ww = win & 7;
        int r = n / 7, s = n - r * 7;
        tb[j] = ((size_t)(b * 58 + wh * 7 + r) * 58 + ww * 7 + s) * 128 + kgsw;
    }
#pragma unroll
    for (int j = 0; j < 8; ++j)
        gB[j] = W2 + (size_t)(wave * 64 + j * 8 + r8) * 1152 + kgsw;

    f32x4 acc[2][8];
#pragma unroll
    for (int m = 0; m < 2; ++m)
#pragma unroll
        for (int n = 0; n < 8; ++n) acc[m][n] = (f32x4){0.f, 0.f, 0.f, 0.f};

    for (int ks = 0; ks < 18; ++ks) {
        int tap = ks >> 1, half = ks & 1;
        int kh = tap / 3, kw = tap - kh * 3;
        int uoff = (kh * 58 + kw) * 128 + half * 64;
#pragma unroll
        for (int j = 0; j < 2; ++j) GLD16(xp + tb[j] + uoff, lsA + (wave * 16 + j * 8) * 64);
#pragma unroll
        for (int j = 0; j < 8; ++j) GLD16(gB[j] + ks * 64, lsB + (wave * 64 + j * 8) * 64);
        __syncthreads();
#pragma unroll
        for (int kk = 0; kk < 2; ++kk) {
            int sl = (((kk << 2) | lq) ^ (lr & 7)) * 8;
            short8 af[2], bf[8];
#pragma unroll
            for (int m = 0; m < 2; ++m)
                af[m] = *(const short8*)&lsA[(wm * 32 + m * 16 + lr) * 64 + sl];
#pragma unroll
            for (int n = 0; n < 8; ++n)
                bf[n] = *(const short8*)&lsB[(wn * 128 + n * 16 + lr) * 64 + sl];
#pragma unroll
            for (int m = 0; m < 2; ++m)
#pragma unroll
                for (int n = 0; n < 8; ++n)
                    acc[m][n] = __builtin_amdgcn_mfma_f32_16x16x32_bf16(af[m], bf[n], acc[m][n], 0, 0, 0);
        }
        __syncthreads();
    }

    float bv[8], gv[8], btv[8];
#pragma unroll
    for (int n = 0; n < 8; ++n) {
        int col = wn * 128 + n * 16 + lr;
        bv[n] = bias[col]; gv[n] = gam[col]; btv[n] = bet[col];
    }
#pragma unroll
    for (int m = 0; m < 2; ++m)
#pragma unroll
        for (int n = 0; n < 8; ++n)
#pragma unroll
            for (int r = 0; r < 4; ++r) acc[m][n][r] += bv[n];

    float* red = (float*)lsA;   // [64][4] = 1KB, safe after final barrier
#pragma unroll
    for (int m = 0; m < 2; ++m)
#pragma unroll
        for (int r = 0; r < 4; ++r) {
            float s = 0.f, qq = 0.f;
#pragma unroll
            for (int n = 0; n < 8; ++n) { float v = acc[m][n][r]; s += v; qq += v * v; }
            s += __shfl_xor(s, 1); s += __shfl_xor(s, 2); s += __shfl_xor(s, 4); s += __shfl_xor(s, 8);
            qq += __shfl_xor(qq, 1); qq += __shfl_xor(qq, 2); qq += __shfl_xor(qq, 4); qq += __shfl_xor(qq, 8);
            if (lr == 0) {
                int row = wm * 32 + m * 16 + lq * 4 + r;
                red[row * 4 + wn * 2] = s; red[row * 4 + wn * 2 + 1] = qq;
            }
        }
    __syncthreads();

#pragma unroll
    for (int m = 0; m < 2; ++m)
#pragma unroll
        for (int r = 0; r < 4; ++r) {
            int row = wm * 32 + m * 16 + lq * 4 + r;
            float S = red[row * 4] + red[row * 4 + 2];
            float Q = red[row * 4 + 1] + red[row * 4 + 3];
            float mean = S * (1.f / 256.f);
            float var = Q * (1.f / 256.f) - mean * mean;
            float inv = rsqrtf(var + 1e-5f);
            size_t grow = (size_t)(mBase + row) * 256;
#pragma unroll
            for (int n = 0; n < 8; ++n) {
                int col = wn * 128 + n * 16 + lr;
                C[grow + col] = f2b((acc[m][n][r] - mean) * inv * gv[n] + btv[n]);
            }
        }
}

// ---------------------------------------------------------------------------
// Fused GEMM (N=256) + bias + LayerNorm: 64x256 tile, BK=64, grid 784.
// ---------------------------------------------------------------------------
__global__ __launch_bounds__(256) void gemm_ln_k(const u16* __restrict__ A, const u16* __restrict__ Bw,
                                                 const float* __restrict__ bias,
                                                 const float* __restrict__ gam, const float* __restrict__ bet,
                                                 u16* __restrict__ C, int K) {
    __shared__ __align__(16) u16 lsA[64 * 64];
    __shared__ __align__(16) u16 lsB[256 * 64];
    int tid = threadIdx.x;
    int wave = tid >> 6, lane = tid & 63;
    int by = xcd_remap1d();
    int mBase = by * 64;
    int wm = wave >> 1, wn = wave & 1;
    int lr = lane & 15, lq = lane >> 4;
    int r8 = lane >> 3, kg = lane & 7;
    int kgsw = ((kg ^ r8) & 7) * 8;

    const u16* gA[2]; const u16* gB[8];
#pragma unroll
    for (int j = 0; j < 2; ++j)
        gA[j] = A + (size_t)(mBase + wave * 16 + j * 8 + r8) * K + kgsw;
#pragma unroll
    for (int j = 0; j < 8; ++j)
        gB[j] = Bw + (size_t)(wave * 64 + j * 8 + r8) * K + kgsw;

    f32x4 acc[2][8];
#pragma unroll
    for (int m = 0; m < 2; ++m)
#pragma unroll
        for (int n = 0; n < 8; ++n) acc[m][n] = (f32x4){0.f, 0.f, 0.f, 0.f};

    for (int k0 = 0; k0 < K; k0 += 64) {
#pragma unroll
        for (int j = 0; j < 2; ++j) GLD16(gA[j] + k0, lsA + (wave * 16 + j * 8) * 64);
#pragma unroll
        for (int j = 0; j < 8; ++j) GLD16(gB[j] + k0, lsB + (wave * 64 + j * 8) * 64);
        __syncthreads();
#pragma unroll
        for (int kk = 0; kk < 2; ++kk) {
            int sl = (((kk << 2) | lq) ^ (lr & 7)) * 8;
            short8 af[2], bf[8];
#pragma unroll
            for (int m = 0; m < 2; ++m)
                af[m] = *(const short8*)&lsA[(wm * 32 + m * 16 + lr) * 64 + sl];
#pragma unroll
            for (int n = 0; n < 8; ++n)
                bf[n] = *(const short8*)&lsB[(wn * 128 + n * 16 + lr) * 64 + sl];
#pragma unroll
            for (int m = 0; m < 2; ++m)
#pragma unroll
                for (int n = 0; n < 8; ++n)
                    acc[m][n] = __builtin_amdgcn_mfma_f32_16x16x32_bf16(af[m], bf[n], acc[m][n], 0, 0, 0);
        }
        __syncthreads();
    }

    float bv[8], gv[8], btv[8];
#pragma unroll
    for (int n = 0; n < 8; ++n) {
        int col = wn * 128 + n * 16 + lr;
        bv[n] = bias[col]; gv[n] = gam[col]; btv[n] = bet[col];
    }
#pragma unroll
    for (int m = 0; m < 2; ++m)
#pragma unroll
        for (int n = 0; n < 8; ++n)
#pragma unroll
            for (int r = 0; r < 4; ++r) acc[m][n][r] += bv[n];

    float* red = (float*)lsA;
#pragma unroll
    for (int m = 0; m < 2; ++m)
#pragma unroll
        for (int r = 0; r < 4; ++r) {
            float s = 0.f, qq = 0.f;
#pragma unroll
            for (int n = 0; n < 8; ++n) { float v = acc[m][n][r]; s += v; qq += v * v; }
            s += __shfl_xor(s, 1); s += __shfl_xor(s, 2); s += __shfl_xor(s, 4); s += __shfl_xor(s, 8);
            qq += __shfl_xor(qq, 1); qq += __shfl_xor(qq, 2); qq += __shfl_xor(qq, 4); qq += __shfl_xor(qq, 8);
            if (lr == 0) {
                int row = wm * 32 + m * 16 + lq * 4 + r;
                red[row * 4 + wn * 2] = s; red[row * 4 + wn * 2 + 1] = qq;
            }
        }
    __syncthreads();

#pragma unroll
    for (int m = 0; m < 2; ++m)
#pragma unroll
        for (int r = 0; r < 4; ++r) {
            int row = wm * 32 + m * 16 + lq * 4 + r;
            float S = red[row * 4] + red[row * 4 + 2];
            float Q = red[row * 4 + 1] + red[row * 4 + 3];
            float mean = S * (1.f / 256.f);
            float var = Q * (1.f / 256.f) - mean * mean;
            float inv = rsqrtf(var + 1e-5f);
            size_t grow = (size_t)(mBase + row) * 256;
#pragma unroll
            for (int n = 0; n < 8; ++n) {
                int col = wn * 128 + n * 16 + lr;
                C[grow + col] = f2b((acc[m][n][r] - mean) * inv * gv[n] + btv[n]);
            }
        }
}

// ---------------------------------------------------------------------------
// GEMM, 2-phase double-buffered: 128x128 tile, BK=32, one barrier per K-step;
// next tile's global_load_lds issued BEFORE compute. Coalesced scalar stores.
// EPI: 0 none, 1 +bias, 2 +bias+gelu(tanh)
// ---------------------------------------------------------------------------
template <int EPI>
__global__ __launch_bounds__(256) void gemm_k(const u16* __restrict__ A, const u16* __restrict__ Bw,
                                              const float* __restrict__ bias, u16* __restrict__ C,
                                              int M, int N, int K) {
    __shared__ __align__(16) u16 lsA[2][128 * 32];
    __shared__ __align__(16) u16 lsB[2][128 * 32];
    int tid = threadIdx.x;
    int wave = tid >> 6, lane = tid & 63;
    int bx, by; xcd_remap(bx, by);
    int mBase = by * 128, nBase = bx * 128;
    int wm = wave >> 1, wn = wave & 1;
    int lr = lane & 15, lq = lane >> 4;
    int rr = lane >> 2, kc = lane & 3;
    int kcs = (kc ^ ((rr >> 1) & 3)) * 8;   // pre-swizzled global chunk (elems)

    const u16* gA[2]; const u16* gB[2];
#pragma unroll
    for (int j = 0; j < 2; ++j) {
        int row = wave * 32 + j * 16 + rr;
        gA[j] = A  + (size_t)(mBase + row) * K + kcs;
        gB[j] = Bw + (size_t)(nBase + row) * K + kcs;
    }

    f32x4 acc[4][4];
#pragma unroll
    for (int m = 0; m < 4; ++m)
#pragma unroll
        for (int n = 0; n < 4; ++n) acc[m][n] = (f32x4){0.f, 0.f, 0.f, 0.f};

    int nk = K >> 5;
#pragma unroll
    for (int j = 0; j < 2; ++j) {
        GLD16(gA[j], &lsA[0][(wave * 32 + j * 16) * 32]);
        GLD16(gB[j], &lsB[0][(wave * 32 + j * 16) * 32]);
    }
    __syncthreads();

    int slq = (lq ^ ((lr >> 1) & 3)) * 8;
    for (int ks = 0; ks < nk; ++ks) {
        int cur = ks & 1;
        if (ks + 1 < nk) {
            int nxt = cur ^ 1;
            int ko = (ks + 1) << 5;
#pragma unroll
            for (int j = 0; j < 2; ++j) {
                GLD16(gA[j] + ko, &lsA[nxt][(wave * 32 + j * 16) * 32]);
                GLD16(gB[j] + ko, &lsB[nxt][(wave * 32 + j * 16) * 32]);
            }
        }
        short8 af[4], bf[4];
#pragma unroll
        for (int m = 0; m < 4; ++m)
            af[m] = *(const short8*)&lsA[cur][(wm * 64 + m * 16 + lr) * 32 + slq];
#pragma unroll
        for (int n = 0; n < 4; ++n)
            bf[n] = *(const short8*)&lsB[cur][(wn * 64 + n * 16 + lr) * 32 + slq];
#pragma unroll
        for (int m = 0; m < 4; ++m)
#pragma unroll
            for (int n = 0; n < 4; ++n)
                acc[m][n] = __builtin_amdgcn_mfma_f32_16x16x32_bf16(af[m], bf[n], acc[m][n], 0, 0, 0);
        __syncthreads();   // drains next-tile loads + guards buffer reuse
    }

#pragma unroll
    for (int m = 0; m < 4; ++m) {
        int row0 = mBase + wm * 64 + m * 16 + lq * 4;
#pragma unroll
        for (int n = 0; n < 4; ++n) {
            int col = nBase + wn * 64 + n * 16 + lr;
            float bv = (EPI >= 1) ? bias[col] : 0.f;
#pragma unroll
            for (int r = 0; r < 4; ++r) {
                float v = acc[m][n][r] + bv;
                if (EPI == 2) {
                    float u = 0.79788456f * (v + 0.044715f * v * v * v);
                    float e = __expf(-2.f * u);
                    v = v * __frcp_rn(1.f + e);
                }
                C[(size_t)(row0 + r) * N + col] = f2b(v);
            }
        }
    }
}

// ---------------------------------------------------------------------------
// MFMA window attention: one wave per (window, head), 4 waves/block.
// ---------------------------------------------------------------------------
__global__ __launch_bounds__(256) void attn_mfma_k(const u16* __restrict__ qkv,
                                                   const float* __restrict__ tab,
                                                   u16* __restrict__ out) {
    __shared__ __align__(16) u16 sh[28488];
    int tid = threadIdx.x;
    int wave = tid >> 6, lane = tid & 63;
    int wh = blockIdx.x * 4 + wave;
    int win = wh >> 3, head = wh & 7;
    int g = lane >> 4, cc = lane & 15;

    u16* Pl = sh + wave * 4608;
    u16* Vl = sh + 18432 + wave * 2176;
    float* bs = (float*)(sh + 27136) + wave * 169;

    const size_t wbase = (size_t)win * 49 * 768;
    for (int e = lane; e < 169; e += 64) bs[e] = tab[e * 8 + head];
    for (int e = lane; e < 49 * 16; e += 64) {
        int k = e >> 4, d0 = (e & 15) * 2;
        *(u32*)&Vl[k * 34 + d0] = *(const u32*)&qkv[wbase + (size_t)k * 768 + 512 + head * 32 + d0];
    }
    for (int e = lane; e < 15 * 16; e += 64) {
        int k = 49 + (e >> 4), d0 = (e & 15) * 2;
        *(u32*)&Vl[k * 34 + d0] = 0u;
    }
    __syncthreads();

    short8 aQ[4], bK[4];
#pragma unroll
    for (int t = 0; t < 4; ++t) {
        int qr = t * 16 + cc; if (qr > 48) qr = 48;
        aQ[t] = *(const short8*)&qkv[wbase + (size_t)qr * 768 + head * 32 + g * 8];
        int kr = t * 16 + cc; if (kr > 48) kr = 48;
        bK[t] = *(const short8*)&qkv[wbase + (size_t)kr * 768 + 256 + head * 32 + g * 8];
    }
    f32x4 S[4][4];
#pragma unroll
    for (int a = 0; a < 4; ++a)
#pragma unroll
        for (int b = 0; b < 4; ++b)
            S[a][b] = __builtin_amdgcn_mfma_f32_16x16x32_bf16(aQ[a], bK[b], (f32x4){0.f,0.f,0.f,0.f}, 0, 0, 0);

    int AqA[4][4];
#pragma unroll
    for (int tr = 0; tr < 4; ++tr)
#pragma unroll
        for (int r = 0; r < 4; ++r) {
            int q = tr * 16 + g * 4 + r; if (q > 48) q = 48;
            int dq = (q * 37) >> 8;
            AqA[tr][r] = 6 * dq + q + 84;
        }
    int AcA[4];
    bool colBad[4];
#pragma unroll
    for (int tc = 0; tc < 4; ++tc) {
        int c = tc * 16 + cc;
        colBad[tc] = (c > 48);
        if (c > 48) c = 48;
        int dc = (c * 37) >> 8;
        AcA[tc] = 6 * dc + c;
    }
    const float scale = 0.17677669529663687f;
    float inv[4][4];
#pragma unroll
    for (int tr = 0; tr < 4; ++tr) {
#pragma unroll
        for (int r = 0; r < 4; ++r) {
            float z0 = colBad[0] ? -1e30f : S[tr][0][r] * scale + bs[AqA[tr][r] - AcA[0]];
            float z1 = colBad[1] ? -1e30f : S[tr][1][r] * scale + bs[AqA[tr][r] - AcA[1]];
            float z2 = colBad[2] ? -1e30f : S[tr][2][r] * scale + bs[AqA[tr][r] - AcA[2]];
            float z3 = colBad[3] ? -1e30f : S[tr][3][r] * scale + bs[AqA[tr][r] - AcA[3]];
            float mx = fmaxf(fmaxf(z0, z1), fmaxf(z2, z3));
            mx = fmaxf(mx, __shfl_xor(mx, 1));
            mx = fmaxf(mx, __shfl_xor(mx, 2));
            mx = fmaxf(mx, __shfl_xor(mx, 4));
            mx = fmaxf(mx, __shfl_xor(mx, 8));
            float p0 = __expf(z0 - mx), p1 = __expf(z1 - mx);
            float p2 = __expf(z2 - mx), p3 = __expf(z3 - mx);
            S[tr][0][r] = p0; S[tr][1][r] = p1; S[tr][2][r] = p2; S[tr][3][r] = p3;
            float sm = p0 + p1 + p2 + p3;
            sm += __shfl_xor(sm, 1); sm += __shfl_xor(sm, 2);
            sm += __shfl_xor(sm, 4); sm += __shfl_xor(sm, 8);
            inv[tr][r] = 1.0f / sm;
        }
    }

#pragma unroll
    for (int tr = 0; tr < 4; ++tr)
#pragma unroll
        for (int tc = 0; tc < 4; ++tc) {
            int k = tc * 16 + cc;
            u16* pb = &Pl[tr * 1152 + k * 18 + g * 4];
            u32 w0 = (u32)f2b(S[tr][tc][0]) | ((u32)f2b(S[tr][tc][1]) << 16);
            u32 w1 = (u32)f2b(S[tr][tc][2]) | ((u32)f2b(S[tr][tc][3]) << 16);
            *(u32*)pb = w0;
            *(u32*)(pb + 2) = w1;
        }
    __syncthreads();

    f32x4 O[4][2];
#pragma unroll
    for (int a = 0; a < 4; ++a) { O[a][0] = (f32x4){0.f,0.f,0.f,0.f}; O[a][1] = (f32x4){0.f,0.f,0.f,0.f}; }
#pragma unroll
    for (int s = 0; s < 2; ++s) {
        short8 pa[4], vb[2];
#pragma unroll
        for (int tr = 0; tr < 4; ++tr)
#pragma unroll
            for (int j = 0; j < 8; ++j)
                pa[tr][j] = (short)Pl[tr * 1152 + (s * 32 + g * 8 + j) * 18 + cc];
#pragma unroll
        for (int td = 0; td < 2; ++td)
#pragma unroll
            for (int j = 0; j < 8; ++j)
                vb[td][j] = (short)Vl[(s * 32 + g * 8 + j) * 34 + td * 16 + cc];
#pragma unroll
        for (int tr = 0; tr < 4; ++tr)
#pragma unroll
            for (int td = 0; td < 2; ++td)
                O[tr][td] = __builtin_amdgcn_mfma_f32_16x16x32_bf16(pa[tr], vb[td], O[tr][td], 0, 0, 0);
    }

#pragma unroll
    for (int tr = 0; tr < 4; ++tr)
#pragma unroll
        for (int r = 0; r < 4; ++r) {
            int q = tr * 16 + g * 4 + r;
            if (q < 49) {
                float iv = inv[tr][r];
                u16* op = out + (size_t)(win * 49 + q) * 256 + head * 32;
                op[cc]      = f2b(O[tr][0][r] * iv);
                op[16 + cc] = f2b(O[tr][1][r] * iv);
            }
        }
}

// ---------------------------------------------------------------------------
// LN3 over 2*x then NCHW fp32 output.
// ---------------------------------------------------------------------------
__global__ __launch_bounds__(256) void ln3_out_k(const u16* __restrict__ f, const float* __restrict__ g3,
                                                 const float* __restrict__ b3, float* __restrict__ out) {
    __shared__ float tile[256][57];
    int bh = blockIdx.x;
    int b = bh / 56, h = bh - b * 56;
    int wv = threadIdx.x >> 6, lane = threadIdx.x & 63;
    int wh = h / 7, r = h - wh * 7;
    float4 gg = *(const float4*)&g3[lane * 4];
    float4 bb = *(const float4*)&b3[lane * 4];
    for (int i = 0; i < 14; ++i) {
        int w = wv + i * 4;
        int wwn = w / 7, s2 = w - wwn * 7;
        int t = (b * 64 + wh * 8 + wwn) * 49 + r * 7 + s2;
        ushort4 u = *(const ushort4*)&f[(size_t)t * 256 + lane * 4];
        float v0 = 2.f * b2f(u.x), v1 = 2.f * b2f(u.y), v2 = 2.f * b2f(u.z), v3 = 2.f * b2f(u.w);
        float s = v0 + v1 + v2 + v3;
        float q = v0 * v0 + v1 * v1 + v2 * v2 + v3 * v3;
#pragma unroll
        for (int o = 32; o; o >>= 1) { s += __shfl_xor(s, o); q += __shfl_xor(q, o); }
        float mean = s * (1.f / 256.f);
        float var = q * (1.f / 256.f) - mean * mean;
        float inv = rsqrtf(var + 1e-5f);
        int c = lane * 4;
        tile[c + 0][w] = (v0 - mean) * inv * gg.x + bb.x;
        tile[c + 1][w] = (v1 - mean) * inv * gg.y + bb.y;
        tile[c + 2][w] = (v2 - mean) * inv * gg.z + bb.z;
        tile[c + 3][w] = (v3 - mean) * inv * gg.w + bb.w;
    }
    __syncthreads();
    size_t obase = (size_t)b * 256 * 3136 + (size_t)h * 56;
#pragma unroll
    for (int it = 0; it < 28; ++it) {
        int e = it * 256 + threadIdx.x;   // 0..7167
        int c = e / 28, wu = e - c * 28;
        float2 pack = make_float2(tile[c][wu * 2], tile[c][wu * 2 + 1]);
        *(float2*)&out[obase + (size_t)c * 3136 + wu * 2] = pack;
    }
}

// ---------------------------------------------------------------------------
extern "C" void kernel_launch(void* const* d_in, const int* in_sizes, int n_in,
                              void* d_out, int out_size, void* d_ws, size_t ws_size,
                              hipStream_t stream) {
    (void)in_sizes; (void)n_in; (void)out_size;
    const float* x      = (const float*)d_in[0];
    const float* conv_w = (const float*)d_in[1];
    const float* conv_b = (const float*)d_in[2];
    const float* g1     = (const float*)d_in[3];
    const float* b1     = (const float*)d_in[4];
    const float* g2     = (const float*)d_in[5];
    const float* b2     = (const float*)d_in[6];
    const float* g3     = (const float*)d_in[7];
    const float* b3     = (const float*)d_in[8];
    const float* qkv_w  = (const float*)d_in[9];
    const float* tab    = (const float*)d_in[10];
    const float* proj_w = (const float*)d_in[11];
    const float* proj_b = (const float*)d_in[12];
    const float* fc1_w  = (const float*)d_in[13];
    const float* fc1_b  = (const float*)d_in[14];
    const float* fc2_w  = (const float*)d_in[15];
    const float* fc2_b  = (const float*)d_in[16];
    float* outp = (float*)d_out;

    // ws layout (bytes) — verified fits: 166,985,728
    const size_t OFF_Y  = (size_t)TTOK * 1152 * 2;           // 115,605,504
    const size_t OFF_AT = OFF_Y + (size_t)TTOK * 512;        // +25,690,112
    const size_t NEED   = OFF_AT + (size_t)TTOK * 512;       // 166,985,728
    if (ws_size < NEED) return;

    char* ws = (char*)d_ws;
    u16* xpad    = (u16*)ws;                 // [16][58][58][128]
    u16* ybuf    = (u16*)(ws + OFF_Y);       // [T][256]
    u16* atout   = (u16*)(ws + OFF_AT);      // [T][256]
    u16* qkvbuf  = (u16*)ws;                 // [T][768]  (overwrites dead xpad)
    u16* hidden  = (u16*)ws;                 // [T][1024] (overwrites dead qkvbuf)
    u16* W2      = atout;                    // dead slot until attn
    u16* wbase   = (u16*)(ws + (size_t)TTOK * 1024 * 2);
    u16* qkvw_b  = wbase;                    // 196,608
    u16* projw_b = wbase + 196608;           //  65,536
    u16* fc1w_b  = projw_b + 65536;          // 262,144
    u16* fc2w_b  = fc1w_b + 262144;          // 262,144

    prep_k<<<2848, 256, 0, stream>>>(x, xpad, conv_w, W2, qkv_w, proj_w, fc1_w, fc2_w, qkvw_b);
    gemm_conv_ln_k<<<784, 256, 0, stream>>>(xpad, W2, conv_b, g1, b1, ybuf);
    gemm_k<0><<<dim3(6, 392), 256, 0, stream>>>(ybuf, qkvw_b, nullptr, qkvbuf, TTOK, 768, 256);
    attn_mfma_k<<<2048, 256, 0, stream>>>(qkvbuf, tab, atout);
    gemm_ln_k<<<784, 256, 0, stream>>>(atout, projw_b, proj_b, g2, b2, ybuf, 256);
    gemm_k<2><<<dim3(8, 392), 256, 0, stream>>>(ybuf, fc1w_b, fc1_b, hidden, TTOK, 1024, 256);
    gemm_k<1><<<dim3(2, 392), 256, 0, stream>>>(hidden, fc2w_b, fc2_b, atout, TTOK, 256, 1024);
    ln3_out_k<<<896, 256, 0, stream>>>(atout, g3, b3, outp);
}